// Round 15
// baseline (73.965 us; speedup 1.0000x reference)
//
#include <hip/hip_runtime.h>
#include <hip/hip_bf16.h>
#include <math.h>

// out[n,:] = s1 .* FWHT( (u/4096) .* FWHT( s2 .* x[n,:] ) ),
// u = g_mu + softplus(g_rho)*epsilon, FWHT = unnormalized Walsh-Hadamard.
//
// R15 = R14 (MFMA formulation, zero LDS) with the inline-asm cvt_pk
// replaced by the R13-PROVEN integer RNE bf16 pack (zero inline asm).
//
// Structure: D = 4096 digits (a,b,c), memory map e = a*256 + c*16 + b.
// One wave per row: 16 register tiles (a) of 16x16 (b,c).
//  - b,c axes: chained MFMAs. Lane l holds T[4*(l>>4)+r][l&15]; one
//    mfma_f32_16x16x32_bf16 with B = H16-fragment computes
//    stage: T -> (H*T)^T (transform hi axis + swap axes), output layout
//    == input layout -> two chained stages give H*T*H with zero
//    cross-lane moves. H16 embedded at j<4 (zeros at j>=4); the result
//    is invariant to the A/B k-slot map since A,B share it.
//  - a axis: in-register pk-FWHT16 over the 16 tiles (f2, proven R5-R13).
// All global I/O uses addr = base + a*256 + (l&15)*16 + (l>>4)*4 (+r):
// each 64B cacheline covered by exactly 4 lanes, full 1KB tile per instr.
// u in natural order (no permutation). 4 bf16 quantization events, f32 acc.

#define WHVI_D 4096

typedef float f2 __attribute__((ext_vector_type(2)));
typedef float f32x4 __attribute__((ext_vector_type(4)));
typedef short bf16x8 __attribute__((ext_vector_type(8)));  // 8 bf16 = 4 VGPRs

__global__ __launch_bounds__(256)
void u_precompute_kernel(const float* __restrict__ g_mu,
                         const float* __restrict__ g_rho,
                         const float* __restrict__ g_eps,
                         float* __restrict__ u) {
    int k = blockIdx.x * 256 + threadIdx.x;  // 0..4095
    float rho = g_rho[k];
    float sp = fmaxf(rho, 0.0f) + __logf(1.0f + __expf(-fabsf(rho)));
    u[k] = (g_mu[k] + sp * g_eps[k]) * (1.0f / 4096.0f);  // natural order
}

// fp32 -> bf16 bits, round-to-nearest-even (R13-proven, pure integer).
__device__ __forceinline__ unsigned bf16_bits(float f) {
    unsigned uu = __builtin_bit_cast(unsigned, f);
    unsigned r = 0x7FFFu + ((uu >> 16) & 1u);
    return (uu + r) >> 16;
}

__device__ __forceinline__ unsigned pack_bf(float a, float b) {
    return bf16_bits(a) | (bf16_bits(b) << 16);
}

__global__ __launch_bounds__(256)
void whvi_mfma_kernel(const float* __restrict__ x,
                      const float* __restrict__ s1,
                      const float* __restrict__ s2,
                      const float* __restrict__ u,
                      float* __restrict__ out,
                      int nrows) {
    const int t = threadIdx.x;
    const int l = t & 63;                 // lane
    const int row = blockIdx.x * 4 + (t >> 6);
    if (row >= nrows) return;

    const int lo = l & 15;                // c-digit slot (tile column)
    const int g4 = (l >> 4) << 2;         // hi-slot base (tile row = g4 + r)
    const int laneoff = lo * 16 + (l >> 4) * 4;
    const size_t base = (size_t)row * WHVI_D + laneoff;

    // ---- H16 fragment as B-operand (constant, +-1 exact in bf16) ----
    // lane l supplies B k-slots j=0..3 with H[g4+j][lo], j>=4 zero.
    uint4 hbits;
    {
        unsigned s0 = (__popc((g4 + 0) & lo) & 1) ? 0xBF80u : 0x3F80u;
        unsigned s1b = (__popc((g4 + 1) & lo) & 1) ? 0xBF80u : 0x3F80u;
        unsigned s2b = (__popc((g4 + 2) & lo) & 1) ? 0xBF80u : 0x3F80u;
        unsigned s3 = (__popc((g4 + 3) & lo) & 1) ? 0xBF80u : 0x3F80u;
        hbits.x = s0 | (s1b << 16);
        hbits.y = s2b | (s3 << 16);
        hbits.z = 0u;
        hbits.w = 0u;
    }
    const bf16x8 Bfrag = __builtin_bit_cast(bf16x8, hbits);

    f2 d[16][2];  // 16 tiles x 4 f32 (2x f2); all indices compile-time

    // ---- load x (16x b128; each instr covers one 1KB tile exactly) ----
#pragma unroll
    for (int a = 0; a < 16; ++a) {
        float4 v = *reinterpret_cast<const float4*>(x + base + a * 256);
        d[a][0] = f2{v.x, v.y};
        d[a][1] = f2{v.z, v.w};
    }
    // ---- s2 scale (same pattern; s2 is 16KB, L2-hot) ----
#pragma unroll
    for (int a = 0; a < 16; ++a) {
        float4 s = *reinterpret_cast<const float4*>(s2 + laneoff + a * 256);
        d[a][0] *= f2{s.x, s.y};
        d[a][1] *= f2{s.z, s.w};
    }

    // One R-stage: quantize held values to the bf16 A-frag (j<4), then
    // D = A*B contracts the tile's hi axis and swaps axes; output layout
    // equals input layout, so stages chain directly.
#define R_STAGE()                                                            \
    do {                                                                     \
        _Pragma("unroll") for (int a = 0; a < 16; ++a) {                     \
            uint4 ab;                                                        \
            ab.x = pack_bf(d[a][0].x, d[a][0].y);                            \
            ab.y = pack_bf(d[a][1].x, d[a][1].y);                            \
            ab.z = 0u;                                                       \
            ab.w = 0u;                                                       \
            bf16x8 A = __builtin_bit_cast(bf16x8, ab);                       \
            f32x4 Dv = __builtin_amdgcn_mfma_f32_16x16x32_bf16(              \
                A, Bfrag, (f32x4){0.f, 0.f, 0.f, 0.f}, 0, 0, 0);             \
            d[a][0] = f2{Dv[0], Dv[1]};                                      \
            d[a][1] = f2{Dv[2], Dv[3]};                                      \
        }                                                                    \
    } while (0)

    // a-axis FWHT16 across the 16 register-resident tiles (pk ops, f32).
#define AFWHT()                                                              \
    do {                                                                     \
        _Pragma("unroll") for (int s = 1; s < 16; s <<= 1) {                 \
            _Pragma("unroll") for (int a = 0; a < 16; ++a) {                 \
                if ((a & s) == 0) {                                          \
                    _Pragma("unroll") for (int p = 0; p < 2; ++p) {          \
                        f2 A = d[a][p], B = d[a | s][p];                     \
                        d[a][p] = A + B;                                     \
                        d[a | s][p] = A - B;                                 \
                    }                                                        \
                }                                                            \
            }                                                                \
        }                                                                    \
    } while (0)

    // ---- FWHT#1: b-axis + c-axis (two MFMA stages), a-axis (VALU) ----
    R_STAGE();
    R_STAGE();
    AFWHT();

    // ---- diagonal u (natural order, same b128 pattern, f32) ----
#pragma unroll
    for (int a = 0; a < 16; ++a) {
        float4 uu = *reinterpret_cast<const float4*>(u + laneoff + a * 256);
        d[a][0] *= f2{uu.x, uu.y};
        d[a][1] *= f2{uu.z, uu.w};
    }

    // ---- FWHT#2: a-axis first (values in regs), then the two MFMA stages ----
    AFWHT();
    R_STAGE();
    R_STAGE();

    // ---- s1 scale + store (same pattern) ----
#pragma unroll
    for (int a = 0; a < 16; ++a) {
        float4 s = *reinterpret_cast<const float4*>(s1 + laneoff + a * 256);
        float4 o;
        o.x = d[a][0].x * s.x;
        o.y = d[a][0].y * s.y;
        o.z = d[a][1].x * s.z;
        o.w = d[a][1].y * s.w;
        *reinterpret_cast<float4*>(out + base + a * 256) = o;
    }
#undef R_STAGE
#undef AFWHT
}

extern "C" void kernel_launch(void* const* d_in, const int* in_sizes, int n_in,
                              void* d_out, int out_size, void* d_ws, size_t ws_size,
                              hipStream_t stream) {
    const float* x     = (const float*)d_in[0];
    const float* s1    = (const float*)d_in[1];
    const float* s2    = (const float*)d_in[2];
    const float* g_mu  = (const float*)d_in[3];
    const float* g_rho = (const float*)d_in[4];
    const float* g_eps = (const float*)d_in[5];
    // d_in[6] is H — unused; the FWHT realizes it exactly.
    float* out = (float*)d_out;

    const int nrows = in_sizes[0] / WHVI_D;  // 8192

    float* u = (float*)d_ws;  // 16 KB workspace
    u_precompute_kernel<<<WHVI_D / 256, 256, 0, stream>>>(g_mu, g_rho, g_eps, u);

    const int nblk = (nrows + 3) / 4;
    whvi_mfma_kernel<<<nblk, 256, 0, stream>>>(x, s1, s2, u, out, nrows);
}